// Round 17
// baseline (5081.463 us; speedup 1.0000x reference)
//
#include <hip/hip_runtime.h>
#include <hip/hip_bf16.h>
#include <math.h>

#define B_ 256
#define T_ 32
#define D_ 500
#define H_ 1024
#define V_ 8000
#define NF_ 512
#define G3H (3*H_)   // 3072
#define G6H (6*H_)   // 6144 (merged fwd+bwd gate row)
#define H2 (2*H_)    // 2048
#define OUTC (H_ + 3*NF_ + V_)   // 10560
#define KPAD 512     // D_ padded to 512 for 16B-aligned bf16 rows
#define NTAP 9
#define NCAT (NTAP*NF_)  // 4608
#define MS 512           // stacked M (fwd 0..255, bwd 256..511)
#define WFRAG_G (64*32*512)   // elements per gate in whh frag layout (1,048,576)
#define WHH_N (3*64*32*64)    // 393216 fragment-vectors per direction

typedef float f32x4 __attribute__((ext_vector_type(4)));
typedef short bf16x8 __attribute__((ext_vector_type(8)));

static __device__ __forceinline__ short f2b(float f) {
    unsigned u = __float_as_uint(f);
    unsigned r = (u + 0x7fffu + ((u >> 16) & 1u)) >> 16;
    return (short)r;
}
static __device__ __forceinline__ float b2f(short s) {
    return __uint_as_float(((unsigned)(unsigned short)s) << 16);
}

// ---------------------------------------------------------------------------
// gemm256r: 256x256-tile bf16 MFMA GEMM (r16-proven).
// ---------------------------------------------------------------------------
template<int MODE>
__global__ __launch_bounds__(512) void gemm256r(
    const short* __restrict__ A, int lda,
    const short* __restrict__ Bt, int ldb,
    const float* __restrict__ bias,
    void* __restrict__ Cv, int ldc, int K)
{
    __shared__ short As[3][256 * 32];
    __shared__ short Bs[3][256 * 32];   // 96 KB total
    const int tid = threadIdx.x;
    const int w = tid >> 6, lane = tid & 63;

    const int nbx = gridDim.x;
    const int R = gridDim.y >> 3;
    const int orig = blockIdx.y * nbx + blockIdx.x;
    const int x = orig & 7;
    const int local = orig >> 3;
    const int seg = local / (R * 3);
    const int rem = local % (R * 3);
    const int mm = rem / 3, nn = rem % 3;
    const int m0 = (x * R + mm) * 256;
    const int n0 = (seg * 3 + nn) * 256;

    const int wm = (w >> 2) * 128;
    const int wn = (w & 3) * 64;

    const int sa = lane & 1, sb = (lane >> 1) & 1, sc = (lane >> 2) & 1;
    const int sd = (lane >> 3) & 1, se = (lane >> 4) & 1, sg = (lane >> 5) & 1;
    const int srow16 = (sc ^ sg) + 2 * sd + 4 * se + 8 * sg;
    const int scol = 8 * ((sa ^ sd) + 2 * (sb ^ se));
    const long aoff0 = (long)(m0 + w * 32 + srow16) * lda + scol;
    const long aoff1 = (long)(m0 + w * 32 + 16 + srow16) * lda + scol;
    const long boff0 = (long)(n0 + w * 32 + srow16) * ldb + scol;
    const long boff1 = (long)(n0 + w * 32 + 16 + srow16) * ldb + scol;

#define STG(t_) do { \
    const int bu_ = (t_) % 3; \
    const long ka_ = (long)(t_) * 32; \
    __builtin_amdgcn_global_load_lds((const __attribute__((address_space(1))) void*)(A + aoff0 + ka_), \
        (__attribute__((address_space(3))) void*)(&As[bu_][(w * 32) * 32]), 16, 0, 0); \
    __builtin_amdgcn_global_load_lds((const __attribute__((address_space(1))) void*)(A + aoff1 + ka_), \
        (__attribute__((address_space(3))) void*)(&As[bu_][(w * 32 + 16) * 32]), 16, 0, 0); \
    __builtin_amdgcn_global_load_lds((const __attribute__((address_space(1))) void*)(Bt + boff0 + ka_), \
        (__attribute__((address_space(3))) void*)(&Bs[bu_][(w * 32) * 32]), 16, 0, 0); \
    __builtin_amdgcn_global_load_lds((const __attribute__((address_space(1))) void*)(Bt + boff1 + ka_), \
        (__attribute__((address_space(3))) void*)(&Bs[bu_][(w * 32 + 16) * 32]), 16, 0, 0); \
} while (0)

    f32x4 acc[8][4];
#pragma unroll
    for (int i = 0; i < 8; ++i)
#pragma unroll
        for (int j = 0; j < 4; ++j) acc[i][j] = (f32x4){0.f, 0.f, 0.f, 0.f};

    const int fr = lane & 15;
    const int fkb = (lane >> 4) * 16;
    const int fxor = ((fr >> 1) & 7) << 4;
    const int T = K >> 5;

    STG(0); STG(1);
    asm volatile("s_waitcnt vmcnt(4)" ::: "memory");
    __builtin_amdgcn_s_barrier();

    for (int t = 0; t < T; ++t) {
        const int bu = t % 3;
        const char* Ab = (const char*)&As[bu][0];
        const char* Bb = (const char*)&Bs[bu][0];

        bf16x8 af[8], bfv[4];
#pragma unroll
        for (int i = 0; i < 8; ++i)
            af[i] = *(const bf16x8*)(Ab + ((((wm + i * 16 + fr) << 6) + fkb) ^ fxor));
#pragma unroll
        for (int j = 0; j < 4; ++j)
            bfv[j] = *(const bf16x8*)(Bb + ((((wn + j * 16 + fr) << 6) + fkb) ^ fxor));

        if (t + 2 < T) STG(t + 2);

#pragma unroll
        for (int i = 0; i < 8; ++i)
#pragma unroll
            for (int j = 0; j < 4; ++j)
                acc[i][j] = __builtin_amdgcn_mfma_f32_16x16x32_bf16(af[i], bfv[j], acc[i][j], 0, 0, 0);

        if (t + 2 < T)      asm volatile("s_waitcnt vmcnt(4)" ::: "memory");
        else if (t + 1 < T) asm volatile("s_waitcnt vmcnt(0)" ::: "memory");
        __builtin_amdgcn_s_barrier();
    }
#undef STG

    const int er = (lane >> 4) * 4, ec = lane & 15;
#pragma unroll
    for (int i = 0; i < 8; ++i) {
#pragma unroll
        for (int j = 0; j < 4; ++j) {
#pragma unroll
            for (int q = 0; q < 4; ++q) {
                const int m = m0 + wm + i * 16 + er + q;
                const int n = n0 + wn + j * 16 + ec;
                const float v = acc[i][j][q];
                if (MODE == 2)
                    ((short*)Cv)[(long)m * ldc + n] = f2b(v + bias[n]);
                else
                    ((_Float16*)Cv)[(long)m * ldc + n] = (_Float16)v;
            }
        }
    }
}

// ---------------------------------------------------------------------------
// m97-structure 128x128 GEMM (small reduce GEMM, mode 0).
// ---------------------------------------------------------------------------
__global__ __launch_bounds__(256) void gemm_bt(
    const short* __restrict__ A, int lda,
    const short* __restrict__ Bt, int ldb,
    const float* __restrict__ bias,
    void* __restrict__ Cv, int ldc,
    int K, int mode)
{
    __shared__ short As[128 * 32];
    __shared__ short Bs[128 * 32];
    const int tid  = threadIdx.x;
    const int w    = tid >> 6, lane = tid & 63;

    const int nbx = gridDim.x;
    const int nwg = nbx * gridDim.y;
    int flat = blockIdx.y * nbx + blockIdx.x;
    flat = (flat & 7) * (nwg >> 3) + (flat >> 3);
    const int m0 = (flat / nbx) * 128, n0 = (flat % nbx) * 128;

    const int wm   = (w >> 1) * 64, wn = (w & 1) * 64;

    f32x4 acc[4][4];
#pragma unroll
    for (int i = 0; i < 4; ++i)
#pragma unroll
        for (int j = 0; j < 4; ++j) acc[i][j] = (f32x4){0.f, 0.f, 0.f, 0.f};

    const int srow = w * 16 + (lane >> 2);
    const int scol = (lane & 3) * 8;
    const long aoff0 = (long)(m0 + srow) * lda + scol;
    const long aoff1 = (long)(m0 + srow + 64) * lda + scol;
    const long boff0 = (long)(n0 + srow) * ldb + scol;
    const long boff1 = (long)(n0 + srow + 64) * ldb + scol;
    short* lA0 = As + w * 512;        short* lA1 = As + 2048 + w * 512;
    short* lB0 = Bs + w * 512;        short* lB1 = Bs + 2048 + w * 512;

    const int fr = lane & 15, fk = (lane >> 4) * 8;

    for (int kt = 0; kt < K; kt += 32) {
        __builtin_amdgcn_global_load_lds((const __attribute__((address_space(1))) void*)(A + aoff0 + kt),
                                         (__attribute__((address_space(3))) void*)lA0, 16, 0, 0);
        __builtin_amdgcn_global_load_lds((const __attribute__((address_space(1))) void*)(A + aoff1 + kt),
                                         (__attribute__((address_space(3))) void*)lA1, 16, 0, 0);
        __builtin_amdgcn_global_load_lds((const __attribute__((address_space(1))) void*)(Bt + boff0 + kt),
                                         (__attribute__((address_space(3))) void*)lB0, 16, 0, 0);
        __builtin_amdgcn_global_load_lds((const __attribute__((address_space(1))) void*)(Bt + boff1 + kt),
                                         (__attribute__((address_space(3))) void*)lB1, 16, 0, 0);
        __syncthreads();
        bf16x8 af[4], bfv[4];
#pragma unroll
        for (int i = 0; i < 4; ++i) af[i]  = *(const bf16x8*)(As + (wm + i * 16 + fr) * 32 + fk);
#pragma unroll
        for (int j = 0; j < 4; ++j) bfv[j] = *(const bf16x8*)(Bs + (wn + j * 16 + fr) * 32 + fk);
#pragma unroll
        for (int i = 0; i < 4; ++i)
#pragma unroll
            for (int j = 0; j < 4; ++j)
                acc[i][j] = __builtin_amdgcn_mfma_f32_16x16x32_bf16(af[i], bfv[j], acc[i][j], 0, 0, 0);
        __syncthreads();
    }

    const int er = (lane >> 4) * 4;
    const int ec = lane & 15;
#pragma unroll
    for (int i = 0; i < 4; ++i) {
#pragma unroll
        for (int j = 0; j < 4; ++j) {
#pragma unroll
            for (int q = 0; q < 4; ++q) {
                const int m = m0 + wm + i * 16 + er + q;
                const int n = n0 + wn + j * 16 + ec;
                float v = acc[i][j][q];
                if (mode == 0) {
                    ((float*)Cv)[(long)m * ldc + n] = v + bias[n];
                } else if (mode == 2) {
                    ((short*)Cv)[(long)m * ldc + n] = f2b(v + bias[n]);
                } else {
                    ((_Float16*)Cv)[(long)m * ldc + n] = (_Float16)v;
                }
            }
        }
    }
}

// ---------------------------------------------------------------------------
// Repack BOTH Whh (fp32 [3H,H]) into contiguous MFMA B-fragment layouts.
// ---------------------------------------------------------------------------
__global__ void repack_whh2(const float* __restrict__ srcf,
                            const float* __restrict__ srcb,
                            short* __restrict__ dst)
{
    const int idx = blockIdx.x * 256 + threadIdx.x;   // 2*393216
    const int h = idx >= WHH_N;
    const int local = idx - h * WHH_N;
    const float* src = h ? srcb : srcf;
    const int l = local & 63;
    const int kt = (local >> 6) & 31;
    const int j16 = (local >> 11) & 63;
    const int g = local >> 17;
    const long srow = ((long)(g << 10) + (j16 << 4) + (l & 15)) * H_ + kt * 32 + ((l >> 4) << 3);
    short o[8];
#pragma unroll
    for (int e = 0; e < 8; ++e) o[e] = f2b(src[srow + e]);
    *(bf16x8*)&dst[(long)idx * 8] = *(bf16x8*)o;
}

// ---------------------------------------------------------------------------
// gru_persistent2: ALL 32 timesteps in ONE ordinary launch, ZERO cross-block
// sync. 32 blocks x 512 thr. Block = (dir = bid&1 [XCD-homogeneous],
// mt = bid>>1) owns m-rows mt*16..+16 x ALL 1024 j -> h never leaves the
// block. h fp32 in registers; bf16 copy staged per step in 32 KB LDS
// (XOR swizzle byte ^= (m&7)<<4 on write AND read). Wave w owns j-slice
// w*128, processed as 2 halves of 4 j16-frags (acc[3][4]).
// B-frags from wfrag (r13-proven layout); epilogue math = r13 verbatim.
// ---------------------------------------------------------------------------
__global__ __launch_bounds__(512) void gru_persistent2(
    const short* __restrict__ wfragf, const short* __restrict__ wfragb,
    const float* __restrict__ bhhf, const float* __restrict__ bhhb,
    const short* __restrict__ xgcat,
    short* __restrict__ gout, const int* __restrict__ lengths)
{
    __shared__ char h_lds[16 * 1024 * 2];   // 32 KB swizzled bf16
    const int tid = threadIdx.x;
    const int w = tid >> 6, lane = tid & 63;
    const int bid = blockIdx.x;          // 0..31
    const int dir = bid & 1;             // same dir per XCD (bid%8 fixed parity)
    const int mt = bid >> 1;             // 0..15
    const short* wfrag = dir ? wfragb : wfragf;
    const float* bhh = dir ? bhhb : bhhf;

    const int fr = lane & 15;            // A row (m) / C col
    const int khi = lane >> 4;           // 0..3
    const int er = khi * 4, ec = fr;
    const int j0w = w * 128;

    // hoisted constants
    float bhr[8], bhz[8], bhn[8];
#pragma unroll
    for (int jf2 = 0; jf2 < 8; ++jf2) {
        const int jj = j0w + jf2 * 16 + ec;
        bhr[jf2] = bhh[jj]; bhz[jf2] = bhh[H_ + jj]; bhn[jf2] = bhh[2 * H_ + jj];
    }
    int lenv[4]; long xb[4];
#pragma unroll
    for (int q = 0; q < 4; ++q) {
        const int b = mt * 16 + er + q;
        lenv[q] = lengths[b];
        xb[q] = (long)b * T_ * G6H + (long)dir * G3H;
    }

    float hreg[8][4];
#pragma unroll
    for (int jf2 = 0; jf2 < 8; ++jf2)
#pragma unroll
        for (int q = 0; q < 4; ++q) hreg[jf2][q] = 0.f;

#define HWRITE() do { \
    _Pragma("unroll") \
    for (int jf2_ = 0; jf2_ < 8; ++jf2_) { \
        _Pragma("unroll") \
        for (int q_ = 0; q_ < 4; ++q_) { \
            const int m_ = er + q_; \
            const int j_ = j0w + jf2_ * 16 + ec; \
            *(short*)(h_lds + ((m_ * 2048 + j_ * 2) ^ ((m_ & 7) << 4))) = f2b(hreg[jf2_][q_]); \
        } \
    } \
} while (0)

    HWRITE();   // h0 = 0

    for (int s = 0; s < T_; ++s) {
        __syncthreads();                  // h_lds ready
        const int tt = dir ? (T_ - 1 - s) : s;
#pragma unroll
        for (int half = 0; half < 2; ++half) {
            f32x4 acc[3][4];
#pragma unroll
            for (int g = 0; g < 3; ++g)
#pragma unroll
                for (int jf = 0; jf < 4; ++jf) acc[g][jf] = (f32x4){0.f, 0.f, 0.f, 0.f};
            const int j16b = w * 8 + half * 4;
#pragma unroll 4
            for (int kt = 0; kt < 32; ++kt) {
                const bf16x8 af = *(const bf16x8*)(h_lds +
                    ((fr * 2048 + kt * 64 + khi * 16) ^ ((fr & 7) << 4)));
#pragma unroll
                for (int g = 0; g < 3; ++g) {
#pragma unroll
                    for (int jf = 0; jf < 4; ++jf) {
                        const bf16x8 bv = *(const bf16x8*)(wfrag + (long)g * WFRAG_G +
                            ((long)(j16b + jf) * 32 + kt) * 512 + lane * 8);
                        acc[g][jf] = __builtin_amdgcn_mfma_f32_16x16x32_bf16(af, bv, acc[g][jf], 0, 0, 0);
                    }
                }
            }
            // epilogue for these 4 j-frags (r13 math)
#pragma unroll
            for (int jf = 0; jf < 4; ++jf) {
                const int jf2 = half * 4 + jf;
                const int jj = j0w + jf2 * 16 + ec;
#pragma unroll
                for (int q = 0; q < 4; ++q) {
                    const short* xrow = xgcat + xb[q] + (long)tt * G6H;
                    const float xr = b2f(xrow[jj]);
                    const float xz = b2f(xrow[H_ + jj]);
                    const float xn = b2f(xrow[2 * H_ + jj]);
                    const float rr = 1.f / (1.f + expf(-(xr + acc[0][jf][q] + bhr[jf2])));
                    const float zz = 1.f / (1.f + expf(-(xz + acc[1][jf][q] + bhz[jf2])));
                    const float nn = tanhf(xn + rr * (acc[2][jf][q] + bhn[jf2]));
                    const float hp = hreg[jf2][q];
                    const float hnew = (1.f - zz) * nn + zz * hp;
                    const bool valid = tt < lenv[q];
                    hreg[jf2][q] = valid ? hnew : hp;
                    const int b = mt * 16 + er + q;
                    gout[((long)b * T_ + tt) * H2 + (long)dir * H_ + jj] = valid ? f2b(hnew) : (short)0;
                }
            }
        }
        __syncthreads();                 // all h_lds reads done
        HWRITE();                        // publish h for step s+1
    }
#undef HWRITE
}

// fp32 -> bf16 with optional K padding (c >= Ksrc -> 0)
__global__ void f2b_pad(const float* __restrict__ src, short* __restrict__ dst,
                        int Ksrc, int Kdst)
{
    const int idx = blockIdx.x * 256 + threadIdx.x;
    const int r = idx / Kdst, c = idx % Kdst;
    dst[idx] = (c < Ksrc) ? f2b(src[(long)r * Ksrc + c]) : (short)0;
}

// both Wih (fp32 [3H, D]) -> contiguous bf16 [2*3H, KPAD] padded
__global__ void wih_pad2(const float* __restrict__ a, const float* __restrict__ b,
                         short* __restrict__ dst)
{
    const int idx = blockIdx.x * 256 + threadIdx.x;   // 2*G3H*KPAD
    const int h = idx >= G3H * KPAD;
    const int rem = idx - h * G3H * KPAD;
    const int r = rem / KPAD, c = rem % KPAD;
    const float* s = h ? b : a;
    dst[idx] = (c < D_) ? f2b(s[(long)r * D_ + c]) : (short)0;
}

// concat two fp32 bias vectors [3072]+[3072] -> [6144]
__global__ void cat_bias(const float* __restrict__ a, const float* __restrict__ b,
                         float* __restrict__ dst)
{
    const int idx = blockIdx.x * 256 + threadIdx.x;   // 6144
    dst[idx] = (idx < G3H) ? a[idx] : b[idx - G3H];
}

// all 9 conv taps: dst row n = tap*NF_ + f, col c; src [NF_,2H,ws]
__global__ void repack_tap_all(const float* __restrict__ cw2,
                               const float* __restrict__ cw3,
                               const float* __restrict__ cw4,
                               short* __restrict__ dst)
{
    const int idx = blockIdx.x * 256 + threadIdx.x;   // 9*NF_*H2
    const int tap = idx / (NF_ * H2);
    const int rem = idx % (NF_ * H2);
    const int f = rem >> 11, c = rem & 2047;
    const float* src; int ws, k;
    if (tap < 2)      { src = cw2; ws = 2; k = tap; }
    else if (tap < 5) { src = cw3; ws = 3; k = tap - 2; }
    else              { src = cw4; ws = 4; k = tap - 5; }
    dst[idx] = f2b(src[((long)(f << 11) + c) * ws + k]);
}

// mean over valid timesteps (gout is zero past length), bf16 in, bf16 out
__global__ void mean_pool2(const short* __restrict__ gin,
                           const int* __restrict__ lengths,
                           short* __restrict__ mean_bf)
{
    const int idx = blockIdx.x * 256 + threadIdx.x;   // B*2H
    const int b = idx >> 11, c = idx & 2047;
    float s = 0.f;
#pragma unroll
    for (int t = 0; t < T_; ++t) s += b2f(gin[((long)(b * T_ + t)) * H2 + c]);
    mean_bf[idx] = f2b(s / (float)lengths[b]);
}

// shifted tap-sum + bias + leaky-relu + max over time
__global__ void conv_max(const _Float16* __restrict__ P,
                         const float* __restrict__ cb2, const float* __restrict__ cb3,
                         const float* __restrict__ cb4, float* __restrict__ out)
{
    const int idx = blockIdx.x * 256 + threadIdx.x;   // B*1536
    const int b = idx / 1536, u0 = idx % 1536;
    int Tout, ws, base, f; float bias;
    if (u0 < 512)       { ws = 2; Tout = 33; base = 0;    f = u0;        bias = cb2[f]; }
    else if (u0 < 1024) { ws = 3; Tout = 34; base = 1024; f = u0 - 512;  bias = cb3[f]; }
    else                { ws = 4; Tout = 35; base = 2560; f = u0 - 1024; bias = cb4[f]; }
    const _Float16* Pb = P + (long)b * T_ * NCAT + base + f;
    float m = -INFINITY;
    for (int u = 0; u < Tout; ++u) {
        float s = bias;
        for (int k = 0; k < ws; ++k) {
            const int t = u - (ws - 1) + k;
            if (t >= 0 && t < T_) s += (float)Pb[(long)t * NCAT + k * NF_];
        }
        s = s > 0.f ? s : 0.01f * s;
        m = fmaxf(m, s);
    }
    out[(long)b * OUTC + H_ + u0] = m;
}

__global__ void bow_copy(const float* __restrict__ bow, float* __restrict__ out)
{
    const int idx = blockIdx.x * 256 + threadIdx.x;   // B * 2000 float4s
    const int b = idx / 2000, q = idx % 2000;
    const float4* src = (const float4*)(bow + (long)b * V_);
    float4* dst = (float4*)(out + (long)b * OUTC + H_ + 3 * NF_);
    dst[q] = src[q];
}

extern "C" void kernel_launch(void* const* d_in, const int* in_sizes, int n_in,
                              void* d_out, int out_size, void* d_ws, size_t ws_size,
                              hipStream_t stream)
{
    const float* text    = (const float*)d_in[0];
    const float* bow     = (const float*)d_in[1];
    const int*   lengths = (const int*)  d_in[2];
    const float* Wih_f   = (const float*)d_in[3];
    const float* Whh_f   = (const float*)d_in[4];
    const float* bih_f   = (const float*)d_in[5];
    const float* bhh_f   = (const float*)d_in[6];
    const float* Wih_b   = (const float*)d_in[7];
    const float* Whh_b   = (const float*)d_in[8];
    const float* bih_b   = (const float*)d_in[9];
    const float* bhh_b   = (const float*)d_in[10];
    const float* W_red   = (const float*)d_in[11];
    const float* b_red   = (const float*)d_in[12];
    const float* cw2     = (const float*)d_in[13];
    const float* cb2     = (const float*)d_in[14];
    const float* cw3     = (const float*)d_in[15];
    const float* cb3     = (const float*)d_in[16];
    const float* cw4     = (const float*)d_in[17];
    const float* cb4     = (const float*)d_in[18];
    float* out = (float*)d_out;

    // ---- workspace layout ----
    char* ws = (char*)d_ws;
    size_t off = 0;
    short* xgcat = (short*)(ws + off); off += (size_t)B_ * T_ * G6H * 2;  // 100.66 MB
    _Float16* P    = (_Float16*)(char*)xgcat;                             // overlay (conv phase)
    short* wtap_bf = (short*)((char*)xgcat + (size_t)B_ * T_ * NCAT * 2); // after P
    short* gin_bf = (short*)(ws + off); off += (size_t)B_ * T_ * H2 * 2;  // 33.55 MB
    short* text_bf = gin_bf;                                              // overlay (proj phase)
    short* wih_bf  = (short*)((char*)gin_bf + (size_t)B_ * T_ * KPAD * 2); // [2*3H][KPAD]
    short* wfrag   = (short*)(ws + off); off += (size_t)2 * 3 * WFRAG_G * 2; // 12.6 MB
    short* wfragf  = wfrag;
    short* wfragb  = wfrag + (size_t)3 * WFRAG_G;
    short* wred_bf = (short*)(ws + off); off += (size_t)H_ * H2 * 2;
    short* gmean_bf= (short*)(ws + off); off += (size_t)B_ * H2 * 2;
    float* bih_cat = (float*)(ws + off); off += (size_t)G6H * 4;

    const dim3 blk(256);

    // ---- conversions / repacks ----
    f2b_pad<<<dim3((B_ * T_ * KPAD) / 256), blk, 0, stream>>>(text, text_bf, D_, KPAD);
    wih_pad2<<<dim3((2 * G3H * KPAD) / 256), blk, 0, stream>>>(Wih_f, Wih_b, wih_bf);
    f2b_pad<<<dim3((H_ * H2) / 256), blk, 0, stream>>>(W_red, wred_bf, H2, H2);
    cat_bias<<<dim3(G6H / 256), blk, 0, stream>>>(bih_f, bih_b, bih_cat);
    repack_whh2<<<dim3((2 * WHH_N) / 256), blk, 0, stream>>>(Whh_f, Whh_b, wfrag);

    // ---- merged input projection (both dirs, N=6144), 256^2 ring GEMM ----
    gemm256r<2><<<dim3(G6H / 256, (B_ * T_) / 256), dim3(512), 0, stream>>>(
        text_bf, KPAD, wih_bf, KPAD, bih_cat, xgcat, G6H, KPAD);

    // ---- bidirectional recurrence: ONE launch, zero cross-block sync ----
    gru_persistent2<<<dim3(32), dim3(512), 0, stream>>>(
        wfragf, wfragb, bhh_f, bhh_b, xgcat, gin_bf, lengths);

    // ---- pooled linear head ----
    mean_pool2<<<dim3((B_ * H2) / 256), blk, 0, stream>>>(gin_bf, lengths, gmean_bf);
    gemm_bt<<<dim3(H_ / 128, B_ / 128), blk, 0, stream>>>(
        gmean_bf, H2, wred_bf, H2, b_red, out, OUTC, H2, 0);

    // ---- conv: repack taps (xgcat dead), one big 256^2 ring GEMM -> fp16 ----
    repack_tap_all<<<dim3((NTAP * NF_ * H2) / 256), blk, 0, stream>>>(cw2, cw3, cw4, wtap_bf);
    gemm256r<3><<<dim3(NCAT / 256, (B_ * T_) / 256), dim3(512), 0, stream>>>(
        gin_bf, H2, wtap_bf, H2, nullptr, P, NCAT, H2);

    conv_max<<<dim3((B_ * 1536) / 256), blk, 0, stream>>>(P, cb2, cb3, cb4, out);
    bow_copy<<<dim3((B_ * 2000) / 256), blk, 0, stream>>>(bow, out);
}

// Round 18
// 946.352 us; speedup vs baseline: 5.3695x; 5.3695x over previous
//
#include <hip/hip_runtime.h>
#include <hip/hip_bf16.h>
#include <math.h>

#define B_ 256
#define T_ 32
#define D_ 500
#define H_ 1024
#define V_ 8000
#define NF_ 512
#define G3H (3*H_)   // 3072
#define G6H (6*H_)   // 6144 (merged fwd+bwd gate row)
#define H2 (2*H_)    // 2048
#define OUTC (H_ + 3*NF_ + V_)   // 10560
#define KPAD 512     // D_ padded to 512 for 16B-aligned bf16 rows
#define NTAP 9
#define NCAT (NTAP*NF_)  // 4608
#define MS 512           // stacked M for recurrence (fwd 0..255, bwd 256..511)
#define WFRAG_G (64*32*512)   // elements per gate in whh frag layout (1,048,576)
#define WHH_N (3*64*32*64)    // 393216 fragment-vectors per direction

typedef float f32x4 __attribute__((ext_vector_type(4)));
typedef short bf16x8 __attribute__((ext_vector_type(8)));

static __device__ __forceinline__ short f2b(float f) {
    unsigned u = __float_as_uint(f);
    unsigned r = (u + 0x7fffu + ((u >> 16) & 1u)) >> 16;
    return (short)r;
}
static __device__ __forceinline__ float b2f(short s) {
    return __uint_as_float(((unsigned)(unsigned short)s) << 16);
}

// ---------------------------------------------------------------------------
// gemm_bt2: 128x128 bf16 MFMA GEMM, T2 LDS XOR-swizzle + 3-buffer counted-
// vmcnt ring + 2D-tiled per-XCD walk (r15-proven, tap GEMM = 188 us).
// Requires gridDim.y % 8 == 0, gridDim.x % 4 == 0, K/32 >= 3.
// MODE 2: bf16 C = bf16(v + bias[n]);  MODE 3: fp16 C = v.
// ---------------------------------------------------------------------------
template<int MODE>
__global__ __launch_bounds__(256) void gemm_bt2(
    const short* __restrict__ A, int lda,
    const short* __restrict__ Bt, int ldb,
    const float* __restrict__ bias,
    void* __restrict__ Cv, int ldc, int K)
{
    __shared__ short As[3][128 * 32];
    __shared__ short Bs[3][128 * 32];   // 48 KB total
    const int tid = threadIdx.x;
    const int w = tid >> 6, lane = tid & 63;

    // XCD-aware mapping with 2D-tiled per-XCD walk (n-blocks of 4)
    const int nbx = gridDim.x;
    const int R = gridDim.y >> 3;        // m-rows per XCD
    const int orig = blockIdx.y * nbx + blockIdx.x;
    const int x = orig & 7;              // XCD id
    const int local = orig >> 3;
    const int seg = local / (R * 4);     // n-block of 4 cols
    const int rem = local % (R * 4);
    const int mm = rem >> 2, nn = rem & 3;
    const int m0 = (x * R + mm) * 128;
    const int n0 = (seg * 4 + nn) * 128;

    const int wm = (w >> 1) * 64, wn = (w & 1) * 64;

    // ---- pre-swizzled staging source coords (r14-proven) ----
    const int sa = lane & 1, sb = (lane >> 1) & 1, sc = (lane >> 2) & 1;
    const int sd = (lane >> 3) & 1, se = (lane >> 4) & 1, sg = (lane >> 5) & 1;
    const int srow = w * 16 + (sc ^ sg) + 2 * sd + 4 * se + 8 * sg;
    const int scol = 8 * ((sa ^ sd) + 2 * (sb ^ se));
    const long aoff0 = (long)(m0 + srow) * lda + scol;
    const long aoff1 = (long)(m0 + srow + 64) * lda + scol;
    const long boff0 = (long)(n0 + srow) * ldb + scol;
    const long boff1 = (long)(n0 + srow + 64) * ldb + scol;

#define STG(t_) do { \
    const int bu_ = (t_) % 3; \
    const long ka_ = (long)(t_) * 32; \
    __builtin_amdgcn_global_load_lds((const __attribute__((address_space(1))) void*)(A + aoff0 + ka_), \
        (__attribute__((address_space(3))) void*)(&As[bu_][w * 512]), 16, 0, 0); \
    __builtin_amdgcn_global_load_lds((const __attribute__((address_space(1))) void*)(A + aoff1 + ka_), \
        (__attribute__((address_space(3))) void*)(&As[bu_][2048 + w * 512]), 16, 0, 0); \
    __builtin_amdgcn_global_load_lds((const __attribute__((address_space(1))) void*)(Bt + boff0 + ka_), \
        (__attribute__((address_space(3))) void*)(&Bs[bu_][w * 512]), 16, 0, 0); \
    __builtin_amdgcn_global_load_lds((const __attribute__((address_space(1))) void*)(Bt + boff1 + ka_), \
        (__attribute__((address_space(3))) void*)(&Bs[bu_][2048 + w * 512]), 16, 0, 0); \
} while (0)

    f32x4 acc[4][4];
#pragma unroll
    for (int i = 0; i < 4; ++i)
#pragma unroll
        for (int j = 0; j < 4; ++j) acc[i][j] = (f32x4){0.f, 0.f, 0.f, 0.f};

    const int fr = lane & 15;
    const int fkb = (lane >> 4) * 16;
    const int fxor = ((fr >> 1) & 7) << 4;
    const int T = K >> 5;

    STG(0); STG(1);
    asm volatile("s_waitcnt vmcnt(4)" ::: "memory");
    __builtin_amdgcn_s_barrier();

    for (int t = 0; t < T; ++t) {
        const int bu = t % 3;
        const char* Ab = (const char*)&As[bu][0];
        const char* Bb = (const char*)&Bs[bu][0];

        bf16x8 af[4], bfv[4];
#pragma unroll
        for (int i = 0; i < 4; ++i)
            af[i] = *(const bf16x8*)(Ab + ((((wm + i * 16 + fr) << 6) + fkb) ^ fxor));
#pragma unroll
        for (int j = 0; j < 4; ++j)
            bfv[j] = *(const bf16x8*)(Bb + ((((wn + j * 16 + fr) << 6) + fkb) ^ fxor));

        if (t + 2 < T) STG(t + 2);

#pragma unroll
        for (int i = 0; i < 4; ++i)
#pragma unroll
            for (int j = 0; j < 4; ++j)
                acc[i][j] = __builtin_amdgcn_mfma_f32_16x16x32_bf16(af[i], bfv[j], acc[i][j], 0, 0, 0);

        if (t + 2 < T)      asm volatile("s_waitcnt vmcnt(4)" ::: "memory");
        else if (t + 1 < T) asm volatile("s_waitcnt vmcnt(0)" ::: "memory");
        __builtin_amdgcn_s_barrier();
    }
#undef STG

    const int er = (lane >> 4) * 4, ec = lane & 15;
#pragma unroll
    for (int i = 0; i < 4; ++i) {
#pragma unroll
        for (int j = 0; j < 4; ++j) {
#pragma unroll
            for (int q = 0; q < 4; ++q) {
                const int m = m0 + wm + i * 16 + er + q;
                const int n = n0 + wn + j * 16 + ec;
                const float v = acc[i][j][q];
                if (MODE == 2)
                    ((short*)Cv)[(long)m * ldc + n] = f2b(v + bias[n]);
                else
                    ((_Float16*)Cv)[(long)m * ldc + n] = (_Float16)v;
            }
        }
    }
}

// ---------------------------------------------------------------------------
// gemm256r: 256x256-tile bf16 MFMA GEMM (r16-proven; used for projection).
// ---------------------------------------------------------------------------
template<int MODE>
__global__ __launch_bounds__(512) void gemm256r(
    const short* __restrict__ A, int lda,
    const short* __restrict__ Bt, int ldb,
    const float* __restrict__ bias,
    void* __restrict__ Cv, int ldc, int K)
{
    __shared__ short As[3][256 * 32];
    __shared__ short Bs[3][256 * 32];   // 96 KB total
    const int tid = threadIdx.x;
    const int w = tid >> 6, lane = tid & 63;

    const int nbx = gridDim.x;
    const int R = gridDim.y >> 3;
    const int orig = blockIdx.y * nbx + blockIdx.x;
    const int x = orig & 7;
    const int local = orig >> 3;
    const int seg = local / (R * 3);
    const int rem = local % (R * 3);
    const int mm = rem / 3, nn = rem % 3;
    const int m0 = (x * R + mm) * 256;
    const int n0 = (seg * 3 + nn) * 256;

    const int wm = (w >> 2) * 128;
    const int wn = (w & 3) * 64;

    const int sa = lane & 1, sb = (lane >> 1) & 1, sc = (lane >> 2) & 1;
    const int sd = (lane >> 3) & 1, se = (lane >> 4) & 1, sg = (lane >> 5) & 1;
    const int srow16 = (sc ^ sg) + 2 * sd + 4 * se + 8 * sg;
    const int scol = 8 * ((sa ^ sd) + 2 * (sb ^ se));
    const long aoff0 = (long)(m0 + w * 32 + srow16) * lda + scol;
    const long aoff1 = (long)(m0 + w * 32 + 16 + srow16) * lda + scol;
    const long boff0 = (long)(n0 + w * 32 + srow16) * ldb + scol;
    const long boff1 = (long)(n0 + w * 32 + 16 + srow16) * ldb + scol;

#define STG(t_) do { \
    const int bu_ = (t_) % 3; \
    const long ka_ = (long)(t_) * 32; \
    __builtin_amdgcn_global_load_lds((const __attribute__((address_space(1))) void*)(A + aoff0 + ka_), \
        (__attribute__((address_space(3))) void*)(&As[bu_][(w * 32) * 32]), 16, 0, 0); \
    __builtin_amdgcn_global_load_lds((const __attribute__((address_space(1))) void*)(A + aoff1 + ka_), \
        (__attribute__((address_space(3))) void*)(&As[bu_][(w * 32 + 16) * 32]), 16, 0, 0); \
    __builtin_amdgcn_global_load_lds((const __attribute__((address_space(1))) void*)(Bt + boff0 + ka_), \
        (__attribute__((address_space(3))) void*)(&Bs[bu_][(w * 32) * 32]), 16, 0, 0); \
    __builtin_amdgcn_global_load_lds((const __attribute__((address_space(1))) void*)(Bt + boff1 + ka_), \
        (__attribute__((address_space(3))) void*)(&Bs[bu_][(w * 32 + 16) * 32]), 16, 0, 0); \
} while (0)

    f32x4 acc[8][4];
#pragma unroll
    for (int i = 0; i < 8; ++i)
#pragma unroll
        for (int j = 0; j < 4; ++j) acc[i][j] = (f32x4){0.f, 0.f, 0.f, 0.f};

    const int fr = lane & 15;
    const int fkb = (lane >> 4) * 16;
    const int fxor = ((fr >> 1) & 7) << 4;
    const int T = K >> 5;

    STG(0); STG(1);
    asm volatile("s_waitcnt vmcnt(4)" ::: "memory");
    __builtin_amdgcn_s_barrier();

    for (int t = 0; t < T; ++t) {
        const int bu = t % 3;
        const char* Ab = (const char*)&As[bu][0];
        const char* Bb = (const char*)&Bs[bu][0];

        bf16x8 af[8], bfv[4];
#pragma unroll
        for (int i = 0; i < 8; ++i)
            af[i] = *(const bf16x8*)(Ab + ((((wm + i * 16 + fr) << 6) + fkb) ^ fxor));
#pragma unroll
        for (int j = 0; j < 4; ++j)
            bfv[j] = *(const bf16x8*)(Bb + ((((wn + j * 16 + fr) << 6) + fkb) ^ fxor));

        if (t + 2 < T) STG(t + 2);

#pragma unroll
        for (int i = 0; i < 8; ++i)
#pragma unroll
            for (int j = 0; j < 4; ++j)
                acc[i][j] = __builtin_amdgcn_mfma_f32_16x16x32_bf16(af[i], bfv[j], acc[i][j], 0, 0, 0);

        if (t + 2 < T)      asm volatile("s_waitcnt vmcnt(4)" ::: "memory");
        else if (t + 1 < T) asm volatile("s_waitcnt vmcnt(0)" ::: "memory");
        __builtin_amdgcn_s_barrier();
    }
#undef STG

    const int er = (lane >> 4) * 4, ec = lane & 15;
#pragma unroll
    for (int i = 0; i < 8; ++i) {
#pragma unroll
        for (int j = 0; j < 4; ++j) {
#pragma unroll
            for (int q = 0; q < 4; ++q) {
                const int m = m0 + wm + i * 16 + er + q;
                const int n = n0 + wn + j * 16 + ec;
                const float v = acc[i][j][q];
                if (MODE == 2)
                    ((short*)Cv)[(long)m * ldc + n] = f2b(v + bias[n]);
                else
                    ((_Float16*)Cv)[(long)m * ldc + n] = (_Float16)v;
            }
        }
    }
}

// ---------------------------------------------------------------------------
// m97-structure 128x128 GEMM (small reduce GEMM, mode 0).
// ---------------------------------------------------------------------------
__global__ __launch_bounds__(256) void gemm_bt(
    const short* __restrict__ A, int lda,
    const short* __restrict__ Bt, int ldb,
    const float* __restrict__ bias,
    void* __restrict__ Cv, int ldc,
    int K, int mode)
{
    __shared__ short As[128 * 32];
    __shared__ short Bs[128 * 32];
    const int tid  = threadIdx.x;
    const int w    = tid >> 6, lane = tid & 63;

    const int nbx = gridDim.x;
    const int nwg = nbx * gridDim.y;
    int flat = blockIdx.y * nbx + blockIdx.x;
    flat = (flat & 7) * (nwg >> 3) + (flat >> 3);
    const int m0 = (flat / nbx) * 128, n0 = (flat % nbx) * 128;

    const int wm   = (w >> 1) * 64, wn = (w & 1) * 64;

    f32x4 acc[4][4];
#pragma unroll
    for (int i = 0; i < 4; ++i)
#pragma unroll
        for (int j = 0; j < 4; ++j) acc[i][j] = (f32x4){0.f, 0.f, 0.f, 0.f};

    const int srow = w * 16 + (lane >> 2);
    const int scol = (lane & 3) * 8;
    const long aoff0 = (long)(m0 + srow) * lda + scol;
    const long aoff1 = (long)(m0 + srow + 64) * lda + scol;
    const long boff0 = (long)(n0 + srow) * ldb + scol;
    const long boff1 = (long)(n0 + srow + 64) * ldb + scol;
    short* lA0 = As + w * 512;        short* lA1 = As + 2048 + w * 512;
    short* lB0 = Bs + w * 512;        short* lB1 = Bs + 2048 + w * 512;

    const int fr = lane & 15, fk = (lane >> 4) * 8;

    for (int kt = 0; kt < K; kt += 32) {
        __builtin_amdgcn_global_load_lds((const __attribute__((address_space(1))) void*)(A + aoff0 + kt),
                                         (__attribute__((address_space(3))) void*)lA0, 16, 0, 0);
        __builtin_amdgcn_global_load_lds((const __attribute__((address_space(1))) void*)(A + aoff1 + kt),
                                         (__attribute__((address_space(3))) void*)lA1, 16, 0, 0);
        __builtin_amdgcn_global_load_lds((const __attribute__((address_space(1))) void*)(Bt + boff0 + kt),
                                         (__attribute__((address_space(3))) void*)lB0, 16, 0, 0);
        __builtin_amdgcn_global_load_lds((const __attribute__((address_space(1))) void*)(Bt + boff1 + kt),
                                         (__attribute__((address_space(3))) void*)lB1, 16, 0, 0);
        __syncthreads();
        bf16x8 af[4], bfv[4];
#pragma unroll
        for (int i = 0; i < 4; ++i) af[i]  = *(const bf16x8*)(As + (wm + i * 16 + fr) * 32 + fk);
#pragma unroll
        for (int j = 0; j < 4; ++j) bfv[j] = *(const bf16x8*)(Bs + (wn + j * 16 + fr) * 32 + fk);
#pragma unroll
        for (int i = 0; i < 4; ++i)
#pragma unroll
            for (int j = 0; j < 4; ++j)
                acc[i][j] = __builtin_amdgcn_mfma_f32_16x16x32_bf16(af[i], bfv[j], acc[i][j], 0, 0, 0);
        __syncthreads();
    }

    const int er = (lane >> 4) * 4;
    const int ec = lane & 15;
#pragma unroll
    for (int i = 0; i < 4; ++i) {
#pragma unroll
        for (int j = 0; j < 4; ++j) {
#pragma unroll
            for (int q = 0; q < 4; ++q) {
                const int m = m0 + wm + i * 16 + er + q;
                const int n = n0 + wn + j * 16 + ec;
                float v = acc[i][j][q];
                if (mode == 0) {
                    ((float*)Cv)[(long)m * ldc + n] = v + bias[n];
                } else if (mode == 2) {
                    ((short*)Cv)[(long)m * ldc + n] = f2b(v + bias[n]);
                } else {
                    ((_Float16*)Cv)[(long)m * ldc + n] = (_Float16)v;
                }
            }
        }
    }
}

// ---------------------------------------------------------------------------
// Repack BOTH Whh (fp32 [3H,H]) into contiguous MFMA B-fragment layouts.
// ---------------------------------------------------------------------------
__global__ void repack_whh2(const float* __restrict__ srcf,
                            const float* __restrict__ srcb,
                            short* __restrict__ dst)
{
    const int idx = blockIdx.x * 256 + threadIdx.x;   // 2*393216
    const int h = idx >= WHH_N;
    const int local = idx - h * WHH_N;
    const float* src = h ? srcb : srcf;
    const int l = local & 63;
    const int kt = (local >> 6) & 31;
    const int j16 = (local >> 11) & 63;
    const int g = local >> 17;
    const long srow = ((long)(g << 10) + (j16 << 4) + (l & 15)) * H_ + kt * 32 + ((l >> 4) << 3);
    short o[8];
#pragma unroll
    for (int e = 0; e < 8; ++e) o[e] = f2b(src[srow + e]);
    *(bf16x8*)&dst[(long)idx * 8] = *(bf16x8*)o;
}

// ---------------------------------------------------------------------------
// One GRU timestep, 2-way K-split (r11/r13-proven). 256 blocks x 512 threads.
// ---------------------------------------------------------------------------
__global__ __launch_bounds__(512) void gru_step_frag(
    const short* __restrict__ hbf_prev, short* __restrict__ hbf_next,
    const float* __restrict__ h32_prev, float* __restrict__ h32_next,
    const short* __restrict__ wfragf, const short* __restrict__ wfragb,
    const float* __restrict__ bhhf, const float* __restrict__ bhhb,
    const short* __restrict__ xgcat,
    short* __restrict__ gout, const int* __restrict__ lengths, int s)
{
    __shared__ f32x4 lacc[4][6][64];   // 24 KB
    const int tid = threadIdx.x;
    const int w8 = tid >> 6;           // 0..7
    const int w = w8 & 3;              // tile wave
    const int khalf = w8 >> 2;         // 0 or 1
    const int lane = tid & 63;
    const int bid = blockIdx.x;
    const int jt = bid & 31;
    const int mtd = bid >> 5;            // 0..7
    const int dir = mtd >> 2, mt = mtd & 3;
    const int m0 = dir * 256 + mt * 64;
    const int j0 = jt * 32;
    const int wm = (w >> 1) * 32, wj = (w & 1) * 16;
    const int tt = dir ? (T_ - 1 - s) : s;

    const short* wfrag = dir ? wfragb : wfragf;
    const float* bhh = dir ? bhhb : bhhf;

    const int fr15 = lane & 15, fk8 = (lane >> 4) * 8;
    const long arow0 = (long)(m0 + wm + fr15) * H_ + fk8 + khalf * 512;
    const long arow1 = arow0 + (long)16 * H_;
    const int j16 = (j0 + wj) >> 4;      // 0..63
    const short* bbase = wfrag + ((long)j16 * 32 + khalf * 16) * 512 + lane * 8;

    f32x4 acc[3][2];
#pragma unroll
    for (int g = 0; g < 3; ++g)
#pragma unroll
        for (int i = 0; i < 2; ++i) acc[g][i] = (f32x4){0.f, 0.f, 0.f, 0.f};

#pragma unroll 4
    for (int kt = 0; kt < 16; ++kt) {
        const bf16x8 af0 = *(const bf16x8*)(hbf_prev + arow0 + kt * 32);
        const bf16x8 af1 = *(const bf16x8*)(hbf_prev + arow1 + kt * 32);
        const bf16x8 b0 = *(const bf16x8*)(bbase + (long)kt * 512);
        const bf16x8 b1 = *(const bf16x8*)(bbase + (long)kt * 512 + WFRAG_G);
        const bf16x8 b2 = *(const bf16x8*)(bbase + (long)kt * 512 + 2 * WFRAG_G);
        acc[0][0] = __builtin_amdgcn_mfma_f32_16x16x32_bf16(af0, b0, acc[0][0], 0, 0, 0);
        acc[0][1] = __builtin_amdgcn_mfma_f32_16x16x32_bf16(af1, b0, acc[0][1], 0, 0, 0);
        acc[1][0] = __builtin_amdgcn_mfma_f32_16x16x32_bf16(af0, b1, acc[1][0], 0, 0, 0);
        acc[1][1] = __builtin_amdgcn_mfma_f32_16x16x32_bf16(af1, b1, acc[1][1], 0, 0, 0);
        acc[2][0] = __builtin_amdgcn_mfma_f32_16x16x32_bf16(af0, b2, acc[2][0], 0, 0, 0);
        acc[2][1] = __builtin_amdgcn_mfma_f32_16x16x32_bf16(af1, b2, acc[2][1], 0, 0, 0);
    }

    if (khalf == 1) {
#pragma unroll
        for (int g = 0; g < 3; ++g)
#pragma unroll
            for (int i = 0; i < 2; ++i)
                lacc[w][g * 2 + i][lane] = acc[g][i];
    }
    __syncthreads();
    if (khalf == 1) return;

#pragma unroll
    for (int g = 0; g < 3; ++g)
#pragma unroll
        for (int i = 0; i < 2; ++i)
            acc[g][i] += lacc[w][g * 2 + i][lane];

    const int er = (lane >> 4) * 4, ec = lane & 15;
    const int jj = j0 + wj + ec;
    const float bhr = bhh[jj], bhz = bhh[H_ + jj], bhn = bhh[2 * H_ + jj];

#pragma unroll
    for (int i = 0; i < 2; ++i) {
#pragma unroll
        for (int q = 0; q < 4; ++q) {
            const int m = m0 + wm + i * 16 + er + q;
            const int b = m & 255;
            const short* xrow = xgcat + ((long)b * T_ + tt) * G6H + (long)dir * G3H;
            const float xr = b2f(xrow[jj]);
            const float xz = b2f(xrow[H_ + jj]);
            const float xn = b2f(xrow[2 * H_ + jj]);
            const float rr = 1.f / (1.f + expf(-(xr + acc[0][i][q] + bhr)));
            const float zz = 1.f / (1.f + expf(-(xz + acc[1][i][q] + bhz)));
            const float nn = tanhf(xn + rr * (acc[2][i][q] + bhn));
            const long hidx = (long)m * H_ + jj;
            const float hp = h32_prev[hidx];
            const float hnew = (1.f - zz) * nn + zz * hp;
            const bool valid = tt < lengths[b];
            const float ho = valid ? hnew : hp;
            h32_next[hidx] = ho;
            hbf_next[hidx] = f2b(ho);
            gout[((long)b * T_ + tt) * H2 + (long)dir * H_ + jj] = valid ? f2b(hnew) : (short)0;
        }
    }
}

// fp32 -> bf16 with optional K padding (c >= Ksrc -> 0)
__global__ void f2b_pad(const float* __restrict__ src, short* __restrict__ dst,
                        int Ksrc, int Kdst)
{
    const int idx = blockIdx.x * 256 + threadIdx.x;
    const int r = idx / Kdst, c = idx % Kdst;
    dst[idx] = (c < Ksrc) ? f2b(src[(long)r * Ksrc + c]) : (short)0;
}

// both Wih (fp32 [3H, D]) -> contiguous bf16 [2*3H, KPAD] padded
__global__ void wih_pad2(const float* __restrict__ a, const float* __restrict__ b,
                         short* __restrict__ dst)
{
    const int idx = blockIdx.x * 256 + threadIdx.x;   // 2*G3H*KPAD
    const int h = idx >= G3H * KPAD;
    const int rem = idx - h * G3H * KPAD;
    const int r = rem / KPAD, c = rem % KPAD;
    const float* s = h ? b : a;
    dst[idx] = (c < D_) ? f2b(s[(long)r * D_ + c]) : (short)0;
}

// concat two fp32 bias vectors [3072]+[3072] -> [6144]
__global__ void cat_bias(const float* __restrict__ a, const float* __restrict__ b,
                         float* __restrict__ dst)
{
    const int idx = blockIdx.x * 256 + threadIdx.x;   // 6144
    dst[idx] = (idx < G3H) ? a[idx] : b[idx - G3H];
}

// all 9 conv taps: dst row n = tap*NF_ + f, col c; src [NF_,2H,ws]
__global__ void repack_tap_all(const float* __restrict__ cw2,
                               const float* __restrict__ cw3,
                               const float* __restrict__ cw4,
                               short* __restrict__ dst)
{
    const int idx = blockIdx.x * 256 + threadIdx.x;   // 9*NF_*H2
    const int tap = idx / (NF_ * H2);
    const int rem = idx % (NF_ * H2);
    const int f = rem >> 11, c = rem & 2047;
    const float* src; int ws, k;
    if (tap < 2)      { src = cw2; ws = 2; k = tap; }
    else if (tap < 5) { src = cw3; ws = 3; k = tap - 2; }
    else              { src = cw4; ws = 4; k = tap - 5; }
    dst[idx] = f2b(src[((long)(f << 11) + c) * ws + k]);
}

// mean over valid timesteps (gout is zero past length), bf16 in, bf16 out
__global__ void mean_pool2(const short* __restrict__ gin,
                           const int* __restrict__ lengths,
                           short* __restrict__ mean_bf)
{
    const int idx = blockIdx.x * 256 + threadIdx.x;   // B*2H
    const int b = idx >> 11, c = idx & 2047;
    float s = 0.f;
#pragma unroll
    for (int t = 0; t < T_; ++t) s += b2f(gin[((long)(b * T_ + t)) * H2 + c]);
    mean_bf[idx] = f2b(s / (float)lengths[b]);
}

// shifted tap-sum + bias + leaky-relu + max over time
__global__ void conv_max(const _Float16* __restrict__ P,
                         const float* __restrict__ cb2, const float* __restrict__ cb3,
                         const float* __restrict__ cb4, float* __restrict__ out)
{
    const int idx = blockIdx.x * 256 + threadIdx.x;   // B*1536
    const int b = idx / 1536, u0 = idx % 1536;
    int Tout, ws, base, f; float bias;
    if (u0 < 512)       { ws = 2; Tout = 33; base = 0;    f = u0;        bias = cb2[f]; }
    else if (u0 < 1024) { ws = 3; Tout = 34; base = 1024; f = u0 - 512;  bias = cb3[f]; }
    else                { ws = 4; Tout = 35; base = 2560; f = u0 - 1024; bias = cb4[f]; }
    const _Float16* Pb = P + (long)b * T_ * NCAT + base + f;
    float m = -INFINITY;
    for (int u = 0; u < Tout; ++u) {
        float s = bias;
        for (int k = 0; k < ws; ++k) {
            const int t = u - (ws - 1) + k;
            if (t >= 0 && t < T_) s += (float)Pb[(long)t * NCAT + k * NF_];
        }
        s = s > 0.f ? s : 0.01f * s;
        m = fmaxf(m, s);
    }
    out[(long)b * OUTC + H_ + u0] = m;
}

__global__ void bow_copy(const float* __restrict__ bow, float* __restrict__ out)
{
    const int idx = blockIdx.x * 256 + threadIdx.x;   // B * 2000 float4s
    const int b = idx / 2000, q = idx % 2000;
    const float4* src = (const float4*)(bow + (long)b * V_);
    float4* dst = (float4*)(out + (long)b * OUTC + H_ + 3 * NF_);
    dst[q] = src[q];
}

extern "C" void kernel_launch(void* const* d_in, const int* in_sizes, int n_in,
                              void* d_out, int out_size, void* d_ws, size_t ws_size,
                              hipStream_t stream)
{
    const float* text    = (const float*)d_in[0];
    const float* bow     = (const float*)d_in[1];
    const int*   lengths = (const int*)  d_in[2];
    const float* Wih_f   = (const float*)d_in[3];
    const float* Whh_f   = (const float*)d_in[4];
    const float* bih_f   = (const float*)d_in[5];
    const float* bhh_f   = (const float*)d_in[6];
    const float* Wih_b   = (const float*)d_in[7];
    const float* Whh_b   = (const float*)d_in[8];
    const float* bih_b   = (const float*)d_in[9];
    const float* bhh_b   = (const float*)d_in[10];
    const float* W_red   = (const float*)d_in[11];
    const float* b_red   = (const float*)d_in[12];
    const float* cw2     = (const float*)d_in[13];
    const float* cb2     = (const float*)d_in[14];
    const float* cw3     = (const float*)d_in[15];
    const float* cb3     = (const float*)d_in[16];
    const float* cw4     = (const float*)d_in[17];
    const float* cb4     = (const float*)d_in[18];
    float* out = (float*)d_out;

    // ---- workspace layout (r13-r16) ----
    char* ws = (char*)d_ws;
    size_t off = 0;
    short* xgcat = (short*)(ws + off); off += (size_t)B_ * T_ * G6H * 2;  // 100.66 MB
    _Float16* P    = (_Float16*)(char*)xgcat;                             // overlay (conv phase)
    short* wtap_bf = (short*)((char*)xgcat + (size_t)B_ * T_ * NCAT * 2); // after P
    short* gin_bf = (short*)(ws + off); off += (size_t)B_ * T_ * H2 * 2;  // 33.55 MB
    short* text_bf = gin_bf;                                              // overlay (proj phase)
    short* wih_bf  = (short*)((char*)gin_bf + (size_t)B_ * T_ * KPAD * 2); // [2*3H][KPAD]
    short* wfrag   = (short*)(ws + off); off += (size_t)2 * 3 * WFRAG_G * 2; // 12.6 MB
    short* wfragf  = wfrag;
    short* wfragb  = wfrag + (size_t)3 * WFRAG_G;
    short* wred_bf = (short*)(ws + off); off += (size_t)H_ * H2 * 2;
    float* h32     = (float*)(ws + off); off += (size_t)2 * MS * H_ * 4;  // ping-pong fp32
    short* h_bf    = (short*)(ws + off); off += (size_t)2 * MS * H_ * 2;  // ping-pong bf16
    short* gmean_bf= (short*)(ws + off); off += (size_t)B_ * H2 * 2;
    float* bih_cat = (float*)(ws + off); off += (size_t)G6H * 4;

    const dim3 blk(256);

    // ---- conversions / repacks (fused) ----
    f2b_pad<<<dim3((B_ * T_ * KPAD) / 256), blk, 0, stream>>>(text, text_bf, D_, KPAD);
    wih_pad2<<<dim3((2 * G3H * KPAD) / 256), blk, 0, stream>>>(Wih_f, Wih_b, wih_bf);
    f2b_pad<<<dim3((H_ * H2) / 256), blk, 0, stream>>>(W_red, wred_bf, H2, H2);
    cat_bias<<<dim3(G6H / 256), blk, 0, stream>>>(bih_f, bih_b, bih_cat);
    repack_whh2<<<dim3((2 * WHH_N) / 256), blk, 0, stream>>>(Whh_f, Whh_b, wfrag);

    // ---- merged input projection (both dirs, N=6144), 256^2 ring GEMM ----
    gemm256r<2><<<dim3(G6H / 256, (B_ * T_) / 256), dim3(512), 0, stream>>>(
        text_bf, KPAD, wih_bf, KPAD, bih_cat, xgcat, G6H, KPAD);

    // ---- stacked bidirectional recurrence: 32 per-step launches ----
    hipMemsetAsync(h32, 0, (size_t)MS * H_ * 4, stream);   // h32 buf0 = 0
    hipMemsetAsync(h_bf, 0, (size_t)MS * H_ * 2, stream);  // h_bf buf0 = 0
    for (int s = 0; s < T_; ++s) {
        const int cur = s & 1, nxt = (s + 1) & 1;
        gru_step_frag<<<dim3(256), dim3(512), 0, stream>>>(
            h_bf + (size_t)cur * MS * H_, h_bf + (size_t)nxt * MS * H_,
            h32 + (size_t)cur * MS * H_, h32 + (size_t)nxt * MS * H_,
            wfragf, wfragb, bhh_f, bhh_b, xgcat,
            gin_bf, lengths, s);
    }

    // ---- pooled linear head ----
    mean_pool2<<<dim3((B_ * H2) / 256), blk, 0, stream>>>(gin_bf, lengths, gmean_bf);
    gemm_bt<<<dim3(H_ / 128, B_ / 128), blk, 0, stream>>>(
        gmean_bf, H2, wred_bf, H2, b_red, out, OUTC, H2, 0);

    // ---- conv: repack taps (xgcat dead), 128^2 ring GEMM (r15: 188us) ----
    repack_tap_all<<<dim3((NTAP * NF_ * H2) / 256), blk, 0, stream>>>(cw2, cw3, cw4, wtap_bf);
    gemm_bt2<3><<<dim3(NCAT / 128, (B_ * T_) / 128), blk, 0, stream>>>(
        gin_bf, H2, wtap_bf, H2, nullptr, P, NCAT, H2);

    conv_max<<<dim3((B_ * 1536) / 256), blk, 0, stream>>>(P, cb2, cb3, cb4, out);
    bow_copy<<<dim3((B_ * 2000) / 256), blk, 0, stream>>>(bow, out);
}

// Round 19
// 920.653 us; speedup vs baseline: 5.5194x; 1.0279x over previous
//
#include <hip/hip_runtime.h>
#include <hip/hip_bf16.h>
#include <math.h>

#define B_ 256
#define T_ 32
#define D_ 500
#define H_ 1024
#define V_ 8000
#define NF_ 512
#define G3H (3*H_)   // 3072
#define G6H (6*H_)   // 6144 (merged fwd+bwd gate row)
#define H2 (2*H_)    // 2048
#define OUTC (H_ + 3*NF_ + V_)   // 10560
#define KPAD 512     // D_ padded to 512 for 16B-aligned bf16 rows
#define NTAP 9
#define NCAT (NTAP*NF_)  // 4608
#define MS 512           // stacked M for recurrence (fwd 0..255, bwd 256..511)
#define WFRAG_G (64*32*512)   // elements per gate in whh frag layout (1,048,576)
#define WHH_N (3*64*32*64)    // 393216 fragment-vectors per direction

// prep_all region boundaries (all multiples of 256)
#define PR0 (B_*T_*KPAD)            // text_bf            4,194,304
#define PR1 (PR0 + 2*G3H*KPAD)      // wih_bf             7,340,032
#define PR2 (PR1 + H_*H2)           // wred_bf            9,437,184
#define PR3 (PR2 + G6H)             // bih_cat            9,443,328
#define PR4 (PR3 + 2*WHH_N)         // wfrag             10,229,760
#define PR5 (PR4 + NTAP*NF_*H2)     // wtap_bf           19,666,944

typedef float f32x4 __attribute__((ext_vector_type(4)));
typedef short bf16x8 __attribute__((ext_vector_type(8)));

static __device__ __forceinline__ short f2b(float f) {
    unsigned u = __float_as_uint(f);
    unsigned r = (u + 0x7fffu + ((u >> 16) & 1u)) >> 16;
    return (short)r;
}
static __device__ __forceinline__ float b2f(short s) {
    return __uint_as_float(((unsigned)(unsigned short)s) << 16);
}

// ---------------------------------------------------------------------------
// gemm_bt2: 128x128 bf16 MFMA GEMM, T2 LDS XOR-swizzle + 3-buffer counted-
// vmcnt ring + 2D-tiled per-XCD walk (r15/r18-proven, tap GEMM = 187 us).
// Requires gridDim.y % 8 == 0, gridDim.x % 4 == 0, K/32 >= 3.
// MODE 2: bf16 C = bf16(v + bias[n]);  MODE 3: fp16 C = v.
// ---------------------------------------------------------------------------
template<int MODE>
__global__ __launch_bounds__(256) void gemm_bt2(
    const short* __restrict__ A, int lda,
    const short* __restrict__ Bt, int ldb,
    const float* __restrict__ bias,
    void* __restrict__ Cv, int ldc, int K)
{
    __shared__ short As[3][128 * 32];
    __shared__ short Bs[3][128 * 32];   // 48 KB total
    const int tid = threadIdx.x;
    const int w = tid >> 6, lane = tid & 63;

    const int nbx = gridDim.x;
    const int R = gridDim.y >> 3;
    const int orig = blockIdx.y * nbx + blockIdx.x;
    const int x = orig & 7;
    const int local = orig >> 3;
    const int seg = local / (R * 4);
    const int rem = local % (R * 4);
    const int mm = rem >> 2, nn = rem & 3;
    const int m0 = (x * R + mm) * 128;
    const int n0 = (seg * 4 + nn) * 128;

    const int wm = (w >> 1) * 64, wn = (w & 1) * 64;

    const int sa = lane & 1, sb = (lane >> 1) & 1, sc = (lane >> 2) & 1;
    const int sd = (lane >> 3) & 1, se = (lane >> 4) & 1, sg = (lane >> 5) & 1;
    const int srow = w * 16 + (sc ^ sg) + 2 * sd + 4 * se + 8 * sg;
    const int scol = 8 * ((sa ^ sd) + 2 * (sb ^ se));
    const long aoff0 = (long)(m0 + srow) * lda + scol;
    const long aoff1 = (long)(m0 + srow + 64) * lda + scol;
    const long boff0 = (long)(n0 + srow) * ldb + scol;
    const long boff1 = (long)(n0 + srow + 64) * ldb + scol;

#define STG(t_) do { \
    const int bu_ = (t_) % 3; \
    const long ka_ = (long)(t_) * 32; \
    __builtin_amdgcn_global_load_lds((const __attribute__((address_space(1))) void*)(A + aoff0 + ka_), \
        (__attribute__((address_space(3))) void*)(&As[bu_][w * 512]), 16, 0, 0); \
    __builtin_amdgcn_global_load_lds((const __attribute__((address_space(1))) void*)(A + aoff1 + ka_), \
        (__attribute__((address_space(3))) void*)(&As[bu_][2048 + w * 512]), 16, 0, 0); \
    __builtin_amdgcn_global_load_lds((const __attribute__((address_space(1))) void*)(Bt + boff0 + ka_), \
        (__attribute__((address_space(3))) void*)(&Bs[bu_][w * 512]), 16, 0, 0); \
    __builtin_amdgcn_global_load_lds((const __attribute__((address_space(1))) void*)(Bt + boff1 + ka_), \
        (__attribute__((address_space(3))) void*)(&Bs[bu_][2048 + w * 512]), 16, 0, 0); \
} while (0)

    f32x4 acc[4][4];
#pragma unroll
    for (int i = 0; i < 4; ++i)
#pragma unroll
        for (int j = 0; j < 4; ++j) acc[i][j] = (f32x4){0.f, 0.f, 0.f, 0.f};

    const int fr = lane & 15;
    const int fkb = (lane >> 4) * 16;
    const int fxor = ((fr >> 1) & 7) << 4;
    const int T = K >> 5;

    STG(0); STG(1);
    asm volatile("s_waitcnt vmcnt(4)" ::: "memory");
    __builtin_amdgcn_s_barrier();

    for (int t = 0; t < T; ++t) {
        const int bu = t % 3;
        const char* Ab = (const char*)&As[bu][0];
        const char* Bb = (const char*)&Bs[bu][0];

        bf16x8 af[4], bfv[4];
#pragma unroll
        for (int i = 0; i < 4; ++i)
            af[i] = *(const bf16x8*)(Ab + ((((wm + i * 16 + fr) << 6) + fkb) ^ fxor));
#pragma unroll
        for (int j = 0; j < 4; ++j)
            bfv[j] = *(const bf16x8*)(Bb + ((((wn + j * 16 + fr) << 6) + fkb) ^ fxor));

        if (t + 2 < T) STG(t + 2);

#pragma unroll
        for (int i = 0; i < 4; ++i)
#pragma unroll
            for (int j = 0; j < 4; ++j)
                acc[i][j] = __builtin_amdgcn_mfma_f32_16x16x32_bf16(af[i], bfv[j], acc[i][j], 0, 0, 0);

        if (t + 2 < T)      asm volatile("s_waitcnt vmcnt(4)" ::: "memory");
        else if (t + 1 < T) asm volatile("s_waitcnt vmcnt(0)" ::: "memory");
        __builtin_amdgcn_s_barrier();
    }
#undef STG

    const int er = (lane >> 4) * 4, ec = lane & 15;
#pragma unroll
    for (int i = 0; i < 4; ++i) {
#pragma unroll
        for (int j = 0; j < 4; ++j) {
#pragma unroll
            for (int q = 0; q < 4; ++q) {
                const int m = m0 + wm + i * 16 + er + q;
                const int n = n0 + wn + j * 16 + ec;
                const float v = acc[i][j][q];
                if (MODE == 2)
                    ((short*)Cv)[(long)m * ldc + n] = f2b(v + bias[n]);
                else
                    ((_Float16*)Cv)[(long)m * ldc + n] = (_Float16)v;
            }
        }
    }
}

// ---------------------------------------------------------------------------
// gemm256r: 256x256-tile bf16 MFMA GEMM (r16-proven; used for projection).
// ---------------------------------------------------------------------------
template<int MODE>
__global__ __launch_bounds__(512) void gemm256r(
    const short* __restrict__ A, int lda,
    const short* __restrict__ Bt, int ldb,
    const float* __restrict__ bias,
    void* __restrict__ Cv, int ldc, int K)
{
    __shared__ short As[3][256 * 32];
    __shared__ short Bs[3][256 * 32];   // 96 KB total
    const int tid = threadIdx.x;
    const int w = tid >> 6, lane = tid & 63;

    const int nbx = gridDim.x;
    const int R = gridDim.y >> 3;
    const int orig = blockIdx.y * nbx + blockIdx.x;
    const int x = orig & 7;
    const int local = orig >> 3;
    const int seg = local / (R * 3);
    const int rem = local % (R * 3);
    const int mm = rem / 3, nn = rem % 3;
    const int m0 = (x * R + mm) * 256;
    const int n0 = (seg * 3 + nn) * 256;

    const int wm = (w >> 2) * 128;
    const int wn = (w & 3) * 64;

    const int sa = lane & 1, sb = (lane >> 1) & 1, sc = (lane >> 2) & 1;
    const int sd = (lane >> 3) & 1, se = (lane >> 4) & 1, sg = (lane >> 5) & 1;
    const int srow16 = (sc ^ sg) + 2 * sd + 4 * se + 8 * sg;
    const int scol = 8 * ((sa ^ sd) + 2 * (sb ^ se));
    const long aoff0 = (long)(m0 + w * 32 + srow16) * lda + scol;
    const long aoff1 = (long)(m0 + w * 32 + 16 + srow16) * lda + scol;
    const long boff0 = (long)(n0 + w * 32 + srow16) * ldb + scol;
    const long boff1 = (long)(n0 + w * 32 + 16 + srow16) * ldb + scol;

#define STG(t_) do { \
    const int bu_ = (t_) % 3; \
    const long ka_ = (long)(t_) * 32; \
    __builtin_amdgcn_global_load_lds((const __attribute__((address_space(1))) void*)(A + aoff0 + ka_), \
        (__attribute__((address_space(3))) void*)(&As[bu_][(w * 32) * 32]), 16, 0, 0); \
    __builtin_amdgcn_global_load_lds((const __attribute__((address_space(1))) void*)(A + aoff1 + ka_), \
        (__attribute__((address_space(3))) void*)(&As[bu_][(w * 32 + 16) * 32]), 16, 0, 0); \
    __builtin_amdgcn_global_load_lds((const __attribute__((address_space(1))) void*)(Bt + boff0 + ka_), \
        (__attribute__((address_space(3))) void*)(&Bs[bu_][(w * 32) * 32]), 16, 0, 0); \
    __builtin_amdgcn_global_load_lds((const __attribute__((address_space(1))) void*)(Bt + boff1 + ka_), \
        (__attribute__((address_space(3))) void*)(&Bs[bu_][(w * 32 + 16) * 32]), 16, 0, 0); \
} while (0)

    f32x4 acc[8][4];
#pragma unroll
    for (int i = 0; i < 8; ++i)
#pragma unroll
        for (int j = 0; j < 4; ++j) acc[i][j] = (f32x4){0.f, 0.f, 0.f, 0.f};

    const int fr = lane & 15;
    const int fkb = (lane >> 4) * 16;
    const int fxor = ((fr >> 1) & 7) << 4;
    const int T = K >> 5;

    STG(0); STG(1);
    asm volatile("s_waitcnt vmcnt(4)" ::: "memory");
    __builtin_amdgcn_s_barrier();

    for (int t = 0; t < T; ++t) {
        const int bu = t % 3;
        const char* Ab = (const char*)&As[bu][0];
        const char* Bb = (const char*)&Bs[bu][0];

        bf16x8 af[8], bfv[4];
#pragma unroll
        for (int i = 0; i < 8; ++i)
            af[i] = *(const bf16x8*)(Ab + ((((wm + i * 16 + fr) << 6) + fkb) ^ fxor));
#pragma unroll
        for (int j = 0; j < 4; ++j)
            bfv[j] = *(const bf16x8*)(Bb + ((((wn + j * 16 + fr) << 6) + fkb) ^ fxor));

        if (t + 2 < T) STG(t + 2);

#pragma unroll
        for (int i = 0; i < 8; ++i)
#pragma unroll
            for (int j = 0; j < 4; ++j)
                acc[i][j] = __builtin_amdgcn_mfma_f32_16x16x32_bf16(af[i], bfv[j], acc[i][j], 0, 0, 0);

        if (t + 2 < T)      asm volatile("s_waitcnt vmcnt(4)" ::: "memory");
        else if (t + 1 < T) asm volatile("s_waitcnt vmcnt(0)" ::: "memory");
        __builtin_amdgcn_s_barrier();
    }
#undef STG

    const int er = (lane >> 4) * 4, ec = lane & 15;
#pragma unroll
    for (int i = 0; i < 8; ++i) {
#pragma unroll
        for (int j = 0; j < 4; ++j) {
#pragma unroll
            for (int q = 0; q < 4; ++q) {
                const int m = m0 + wm + i * 16 + er + q;
                const int n = n0 + wn + j * 16 + ec;
                const float v = acc[i][j][q];
                if (MODE == 2)
                    ((short*)Cv)[(long)m * ldc + n] = f2b(v + bias[n]);
                else
                    ((_Float16*)Cv)[(long)m * ldc + n] = (_Float16)v;
            }
        }
    }
}

// ---------------------------------------------------------------------------
// m97-structure 128x128 GEMM (small reduce GEMM, mode 0).
// ---------------------------------------------------------------------------
__global__ __launch_bounds__(256) void gemm_bt(
    const short* __restrict__ A, int lda,
    const short* __restrict__ Bt, int ldb,
    const float* __restrict__ bias,
    void* __restrict__ Cv, int ldc,
    int K, int mode)
{
    __shared__ short As[128 * 32];
    __shared__ short Bs[128 * 32];
    const int tid  = threadIdx.x;
    const int w    = tid >> 6, lane = tid & 63;

    const int nbx = gridDim.x;
    const int nwg = nbx * gridDim.y;
    int flat = blockIdx.y * nbx + blockIdx.x;
    flat = (flat & 7) * (nwg >> 3) + (flat >> 3);
    const int m0 = (flat / nbx) * 128, n0 = (flat % nbx) * 128;

    const int wm   = (w >> 1) * 64, wn = (w & 1) * 64;

    f32x4 acc[4][4];
#pragma unroll
    for (int i = 0; i < 4; ++i)
#pragma unroll
        for (int j = 0; j < 4; ++j) acc[i][j] = (f32x4){0.f, 0.f, 0.f, 0.f};

    const int srow = w * 16 + (lane >> 2);
    const int scol = (lane & 3) * 8;
    const long aoff0 = (long)(m0 + srow) * lda + scol;
    const long aoff1 = (long)(m0 + srow + 64) * lda + scol;
    const long boff0 = (long)(n0 + srow) * ldb + scol;
    const long boff1 = (long)(n0 + srow + 64) * ldb + scol;
    short* lA0 = As + w * 512;        short* lA1 = As + 2048 + w * 512;
    short* lB0 = Bs + w * 512;        short* lB1 = Bs + 2048 + w * 512;

    const int fr = lane & 15, fk = (lane >> 4) * 8;

    for (int kt = 0; kt < K; kt += 32) {
        __builtin_amdgcn_global_load_lds((const __attribute__((address_space(1))) void*)(A + aoff0 + kt),
                                         (__attribute__((address_space(3))) void*)lA0, 16, 0, 0);
        __builtin_amdgcn_global_load_lds((const __attribute__((address_space(1))) void*)(A + aoff1 + kt),
                                         (__attribute__((address_space(3))) void*)lA1, 16, 0, 0);
        __builtin_amdgcn_global_load_lds((const __attribute__((address_space(1))) void*)(Bt + boff0 + kt),
                                         (__attribute__((address_space(3))) void*)lB0, 16, 0, 0);
        __builtin_amdgcn_global_load_lds((const __attribute__((address_space(1))) void*)(Bt + boff1 + kt),
                                         (__attribute__((address_space(3))) void*)lB1, 16, 0, 0);
        __syncthreads();
        bf16x8 af[4], bfv[4];
#pragma unroll
        for (int i = 0; i < 4; ++i) af[i]  = *(const bf16x8*)(As + (wm + i * 16 + fr) * 32 + fk);
#pragma unroll
        for (int j = 0; j < 4; ++j) bfv[j] = *(const bf16x8*)(Bs + (wn + j * 16 + fr) * 32 + fk);
#pragma unroll
        for (int i = 0; i < 4; ++i)
#pragma unroll
            for (int j = 0; j < 4; ++j)
                acc[i][j] = __builtin_amdgcn_mfma_f32_16x16x32_bf16(af[i], bfv[j], acc[i][j], 0, 0, 0);
        __syncthreads();
    }

    const int er = (lane >> 4) * 4;
    const int ec = lane & 15;
#pragma unroll
    for (int i = 0; i < 4; ++i) {
#pragma unroll
        for (int j = 0; j < 4; ++j) {
#pragma unroll
            for (int q = 0; q < 4; ++q) {
                const int m = m0 + wm + i * 16 + er + q;
                const int n = n0 + wn + j * 16 + ec;
                float v = acc[i][j][q];
                if (mode == 0) {
                    ((float*)Cv)[(long)m * ldc + n] = v + bias[n];
                } else if (mode == 2) {
                    ((short*)Cv)[(long)m * ldc + n] = f2b(v + bias[n]);
                } else {
                    ((_Float16*)Cv)[(long)m * ldc + n] = (_Float16)v;
                }
            }
        }
    }
}

// ---------------------------------------------------------------------------
// prep_all: ALL input conversions/repacks in ONE launch (regions are
// launch-independent; every boundary is a multiple of 256 -> no divergence).
// ---------------------------------------------------------------------------
__global__ void prep_all(
    const float* __restrict__ text,
    const float* __restrict__ Wih_f, const float* __restrict__ Wih_b,
    const float* __restrict__ W_red,
    const float* __restrict__ bih_f, const float* __restrict__ bih_b,
    const float* __restrict__ Whh_f, const float* __restrict__ Whh_b,
    const float* __restrict__ cw2, const float* __restrict__ cw3,
    const float* __restrict__ cw4,
    short* __restrict__ text_bf, short* __restrict__ wih_bf,
    short* __restrict__ wred_bf, float* __restrict__ bih_cat,
    short* __restrict__ wfrag, short* __restrict__ wtap_bf)
{
    const int gidx = blockIdx.x * 256 + threadIdx.x;

    if (gidx < PR0) {                    // text -> bf16 padded [8192][512]
        const int idx = gidx;
        const int r = idx / KPAD, c = idx % KPAD;
        text_bf[idx] = (c < D_) ? f2b(text[(long)r * D_ + c]) : (short)0;
    } else if (gidx < PR1) {             // both Wih -> bf16 padded [6144][512]
        const int idx = gidx - PR0;
        const int h = idx >= G3H * KPAD;
        const int rem = idx - h * G3H * KPAD;
        const int r = rem / KPAD, c = rem % KPAD;
        const float* s = h ? Wih_b : Wih_f;
        wih_bf[idx] = (c < D_) ? f2b(s[(long)r * D_ + c]) : (short)0;
    } else if (gidx < PR2) {             // W_red -> bf16 [1024][2048]
        const int idx = gidx - PR1;
        wred_bf[idx] = f2b(W_red[idx]);
    } else if (gidx < PR3) {             // bias concat [6144]
        const int idx = gidx - PR2;
        bih_cat[idx] = (idx < G3H) ? bih_f[idx] : bih_b[idx - G3H];
    } else if (gidx < PR4) {             // both Whh -> fragment layout
        const int idx = gidx - PR3;
        const int h = idx >= WHH_N;
        const int local = idx - h * WHH_N;
        const float* src = h ? Whh_b : Whh_f;
        const int l = local & 63;
        const int kt = (local >> 6) & 31;
        const int j16 = (local >> 11) & 63;
        const int g = local >> 17;
        const long srow = ((long)(g << 10) + (j16 << 4) + (l & 15)) * H_ + kt * 32 + ((l >> 4) << 3);
        short o[8];
#pragma unroll
        for (int e = 0; e < 8; ++e) o[e] = f2b(src[srow + e]);
        *(bf16x8*)&wfrag[(long)idx * 8] = *(bf16x8*)o;
    } else {                             // all 9 conv taps
        const int idx = gidx - PR4;
        const int tap = idx / (NF_ * H2);
        const int rem = idx % (NF_ * H2);
        const int f = rem >> 11, c = rem & 2047;
        const float* src; int ws, k;
        if (tap < 2)      { src = cw2; ws = 2; k = tap; }
        else if (tap < 5) { src = cw3; ws = 3; k = tap - 2; }
        else              { src = cw4; ws = 4; k = tap - 5; }
        wtap_bf[idx] = f2b(src[((long)(f << 11) + c) * ws + k]);
    }
}

// ---------------------------------------------------------------------------
// One GRU timestep, 2-way K-split (r11/r13-proven) + step-0 fast path
// (h0 == 0 algebraically -> skip K-loop and h reads; no memset needed).
// 256 blocks x 512 threads.
// ---------------------------------------------------------------------------
__global__ __launch_bounds__(512) void gru_step_frag(
    const short* __restrict__ hbf_prev, short* __restrict__ hbf_next,
    const float* __restrict__ h32_prev, float* __restrict__ h32_next,
    const short* __restrict__ wfragf, const short* __restrict__ wfragb,
    const float* __restrict__ bhhf, const float* __restrict__ bhhb,
    const short* __restrict__ xgcat,
    short* __restrict__ gout, const int* __restrict__ lengths, int s)
{
    __shared__ f32x4 lacc[4][6][64];   // 24 KB
    const int tid = threadIdx.x;
    const int w8 = tid >> 6;           // 0..7
    const int w = w8 & 3;              // tile wave
    const int khalf = w8 >> 2;         // 0 or 1
    const int lane = tid & 63;
    const int bid = blockIdx.x;
    const int jt = bid & 31;
    const int mtd = bid >> 5;            // 0..7
    const int dir = mtd >> 2, mt = mtd & 3;
    const int m0 = dir * 256 + mt * 64;
    const int j0 = jt * 32;
    const int wm = (w >> 1) * 32, wj = (w & 1) * 16;
    const int tt = dir ? (T_ - 1 - s) : s;

    const short* wfrag = dir ? wfragb : wfragf;
    const float* bhh = dir ? bhhb : bhhf;

    const int fr15 = lane & 15, fk8 = (lane >> 4) * 8;
    const long arow0 = (long)(m0 + wm + fr15) * H_ + fk8 + khalf * 512;
    const long arow1 = arow0 + (long)16 * H_;
    const int j16 = (j0 + wj) >> 4;      // 0..63
    const short* bbase = wfrag + ((long)j16 * 32 + khalf * 16) * 512 + lane * 8;

    f32x4 acc[3][2];
#pragma unroll
    for (int g = 0; g < 3; ++g)
#pragma unroll
        for (int i = 0; i < 2; ++i) acc[g][i] = (f32x4){0.f, 0.f, 0.f, 0.f};

    if (s != 0) {
#pragma unroll 4
        for (int kt = 0; kt < 16; ++kt) {
            const bf16x8 af0 = *(const bf16x8*)(hbf_prev + arow0 + kt * 32);
            const bf16x8 af1 = *(const bf16x8*)(hbf_prev + arow1 + kt * 32);
            const bf16x8 b0 = *(const bf16x8*)(bbase + (long)kt * 512);
            const bf16x8 b1 = *(const bf16x8*)(bbase + (long)kt * 512 + WFRAG_G);
            const bf16x8 b2 = *(const bf16x8*)(bbase + (long)kt * 512 + 2 * WFRAG_G);
            acc[0][0] = __builtin_amdgcn_mfma_f32_16x16x32_bf16(af0, b0, acc[0][0], 0, 0, 0);
            acc[0][1] = __builtin_amdgcn_mfma_f32_16x16x32_bf16(af1, b0, acc[0][1], 0, 0, 0);
            acc[1][0] = __builtin_amdgcn_mfma_f32_16x16x32_bf16(af0, b1, acc[1][0], 0, 0, 0);
            acc[1][1] = __builtin_amdgcn_mfma_f32_16x16x32_bf16(af1, b1, acc[1][1], 0, 0, 0);
            acc[2][0] = __builtin_amdgcn_mfma_f32_16x16x32_bf16(af0, b2, acc[2][0], 0, 0, 0);
            acc[2][1] = __builtin_amdgcn_mfma_f32_16x16x32_bf16(af1, b2, acc[2][1], 0, 0, 0);
        }
    }

    if (khalf == 1) {
#pragma unroll
        for (int g = 0; g < 3; ++g)
#pragma unroll
            for (int i = 0; i < 2; ++i)
                lacc[w][g * 2 + i][lane] = acc[g][i];
    }
    __syncthreads();
    if (khalf == 1) return;

#pragma unroll
    for (int g = 0; g < 3; ++g)
#pragma unroll
        for (int i = 0; i < 2; ++i)
            acc[g][i] += lacc[w][g * 2 + i][lane];

    const int er = (lane >> 4) * 4, ec = lane & 15;
    const int jj = j0 + wj + ec;
    const float bhr = bhh[jj], bhz = bhh[H_ + jj], bhn = bhh[2 * H_ + jj];

#pragma unroll
    for (int i = 0; i < 2; ++i) {
#pragma unroll
        for (int q = 0; q < 4; ++q) {
            const int m = m0 + wm + i * 16 + er + q;
            const int b = m & 255;
            const short* xrow = xgcat + ((long)b * T_ + tt) * G6H + (long)dir * G3H;
            const float xr = b2f(xrow[jj]);
            const float xz = b2f(xrow[H_ + jj]);
            const float xn = b2f(xrow[2 * H_ + jj]);
            const float rr = 1.f / (1.f + expf(-(xr + acc[0][i][q] + bhr)));
            const float zz = 1.f / (1.f + expf(-(xz + acc[1][i][q] + bhz)));
            const float nn = tanhf(xn + rr * (acc[2][i][q] + bhn));
            const long hidx = (long)m * H_ + jj;
            const float hp = (s != 0) ? h32_prev[hidx] : 0.f;
            const float hnew = (1.f - zz) * nn + zz * hp;
            const bool valid = tt < lengths[b];
            const float ho = valid ? hnew : hp;
            h32_next[hidx] = ho;
            hbf_next[hidx] = f2b(ho);
            gout[((long)b * T_ + tt) * H2 + (long)dir * H_ + jj] = valid ? f2b(hnew) : (short)0;
        }
    }
}

// mean over valid timesteps (gout is zero past length), bf16 in, bf16 out
__global__ void mean_pool2(const short* __restrict__ gin,
                           const int* __restrict__ lengths,
                           short* __restrict__ mean_bf)
{
    const int idx = blockIdx.x * 256 + threadIdx.x;   // B*2H
    const int b = idx >> 11, c = idx & 2047;
    float s = 0.f;
#pragma unroll
    for (int t = 0; t < T_; ++t) s += b2f(gin[((long)(b * T_ + t)) * H2 + c]);
    mean_bf[idx] = f2b(s / (float)lengths[b]);
}

// fused tail: conv shifted tap-sum + leaky + time-max, then bow copy.
// region boundary 393216 is a multiple of 256 -> no intra-block divergence.
__global__ void tail_fuse(const _Float16* __restrict__ P,
                          const float* __restrict__ cb2, const float* __restrict__ cb3,
                          const float* __restrict__ cb4,
                          const float* __restrict__ bow, float* __restrict__ out)
{
    const int gidx = blockIdx.x * 256 + threadIdx.x;
    if (gidx < B_ * 1536) {
        const int b = gidx / 1536, u0 = gidx % 1536;
        int Tout, ws, base, f; float bias;
        if (u0 < 512)       { ws = 2; Tout = 33; base = 0;    f = u0;        bias = cb2[f]; }
        else if (u0 < 1024) { ws = 3; Tout = 34; base = 1024; f = u0 - 512;  bias = cb3[f]; }
        else                { ws = 4; Tout = 35; base = 2560; f = u0 - 1024; bias = cb4[f]; }
        const _Float16* Pb = P + (long)b * T_ * NCAT + base + f;
        float m = -INFINITY;
        for (int u = 0; u < Tout; ++u) {
            float s = bias;
            for (int k = 0; k < ws; ++k) {
                const int t = u - (ws - 1) + k;
                if (t >= 0 && t < T_) s += (float)Pb[(long)t * NCAT + k * NF_];
            }
            s = s > 0.f ? s : 0.01f * s;
            m = fmaxf(m, s);
        }
        out[(long)b * OUTC + H_ + u0] = m;
    } else {
        const int idx = gidx - B_ * 1536;   // B * 2000 float4s
        const int b = idx / 2000, q = idx % 2000;
        const float4* src = (const float4*)(bow + (long)b * V_);
        float4* dst = (float4*)(out + (long)b * OUTC + H_ + 3 * NF_);
        dst[q] = src[q];
    }
}

extern "C" void kernel_launch(void* const* d_in, const int* in_sizes, int n_in,
                              void* d_out, int out_size, void* d_ws, size_t ws_size,
                              hipStream_t stream)
{
    const float* text    = (const float*)d_in[0];
    const float* bow     = (const float*)d_in[1];
    const int*   lengths = (const int*)  d_in[2];
    const float* Wih_f   = (const float*)d_in[3];
    const float* Whh_f   = (const float*)d_in[4];
    const float* bih_f   = (const float*)d_in[5];
    const float* bhh_f   = (const float*)d_in[6];
    const float* Wih_b   = (const float*)d_in[7];
    const float* Whh_b   = (const float*)d_in[8];
    const float* bih_b   = (const float*)d_in[9];
    const float* bhh_b   = (const float*)d_in[10];
    const float* W_red   = (const float*)d_in[11];
    const float* b_red   = (const float*)d_in[12];
    const float* cw2     = (const float*)d_in[13];
    const float* cb2     = (const float*)d_in[14];
    const float* cw3     = (const float*)d_in[15];
    const float* cb3     = (const float*)d_in[16];
    const float* cw4     = (const float*)d_in[17];
    const float* cb4     = (const float*)d_in[18];
    float* out = (float*)d_out;

    // ---- workspace layout ----
    char* ws = (char*)d_ws;
    size_t off = 0;
    short* xgcat = (short*)(ws + off); off += (size_t)B_ * T_ * G6H * 2;  // 100.66 MB
    _Float16* P    = (_Float16*)(char*)xgcat;                             // overlay (conv phase)
    short* gin_bf = (short*)(ws + off); off += (size_t)B_ * T_ * H2 * 2;  // 33.55 MB
    short* text_bf = gin_bf;                                              // overlay (proj phase)
    short* wih_bf  = (short*)((char*)gin_bf + (size_t)B_ * T_ * KPAD * 2); // [6144][512]
    short* wtap_bf = (short*)(ws + off); off += (size_t)NTAP * NF_ * H2 * 2; // 9.44 MB (own buffer)
    short* wfrag   = (short*)(ws + off); off += (size_t)2 * 3 * WFRAG_G * 2; // 12.6 MB
    short* wfragf  = wfrag;
    short* wfragb  = wfrag + (size_t)3 * WFRAG_G;
    short* wred_bf = (short*)(ws + off); off += (size_t)H_ * H2 * 2;
    float* h32     = (float*)(ws + off); off += (size_t)2 * MS * H_ * 4;  // ping-pong fp32
    short* h_bf    = (short*)(ws + off); off += (size_t)2 * MS * H_ * 2;  // ping-pong bf16
    short* gmean_bf= (short*)(ws + off); off += (size_t)B_ * H2 * 2;
    float* bih_cat = (float*)(ws + off); off += (size_t)G6H * 4;

    const dim3 blk(256);

    // ---- all conversions / repacks: ONE launch ----
    prep_all<<<dim3(PR5 / 256), blk, 0, stream>>>(
        text, Wih_f, Wih_b, W_red, bih_f, bih_b, Whh_f, Whh_b,
        cw2, cw3, cw4,
        text_bf, wih_bf, wred_bf, bih_cat, wfrag, wtap_bf);

    // ---- merged input projection (both dirs, N=6144), 256^2 ring GEMM ----
    gemm256r<2><<<dim3(G6H / 256, (B_ * T_) / 256), dim3(512), 0, stream>>>(
        text_bf, KPAD, wih_bf, KPAD, bih_cat, xgcat, G6H, KPAD);

    // ---- stacked bidirectional recurrence: 32 per-step launches ----
    // (step 0 has an in-kernel h==0 fast path; no memset needed)
    for (int s = 0; s < T_; ++s) {
        const int cur = s & 1, nxt = (s + 1) & 1;
        gru_step_frag<<<dim3(256), dim3(512), 0, stream>>>(
            h_bf + (size_t)cur * MS * H_, h_bf + (size_t)nxt * MS * H_,
            h32 + (size_t)cur * MS * H_, h32 + (size_t)nxt * MS * H_,
            wfragf, wfragb, bhh_f, bhh_b, xgcat,
            gin_bf, lengths, s);
    }

    // ---- pooled linear head ----
    mean_pool2<<<dim3((B_ * H2) / 256), blk, 0, stream>>>(gin_bf, lengths, gmean_bf);
    gemm_bt<<<dim3(H_ / 128, B_ / 128), blk, 0, stream>>>(
        gmean_bf, H2, wred_bf, H2, b_red, out, OUTC, H2, 0);

    // ---- conv: one big 128^2 ring GEMM -> fp16 partials ----
    gemm_bt2<3><<<dim3(NCAT / 128, (B_ * T_) / 128), blk, 0, stream>>>(
        gin_bf, H2, wtap_bf, H2, nullptr, P, NCAT, H2);

    // ---- fused conv-max + bow copy ----
    tail_fuse<<<dim3((B_ * 1536 + B_ * 2000) / 256), blk, 0, stream>>>(
        P, cb2, cb3, cb4, bow, out);
}